// Round 5
// baseline (194.681 us; speedup 1.0000x reference)
//
#include <hip/hip_runtime.h>
#include <stdint.h>

#define T_LEN 2048

typedef __attribute__((ext_vector_type(8))) short bf16x8;
typedef __attribute__((ext_vector_type(16))) float f32x16;

// RNE fp32 pair -> packed bf16x2 (inputs finite normals)
static __device__ __forceinline__ unsigned pack_bf16(float a, float b) {
    unsigned ua = __float_as_uint(a);
    unsigned ub = __float_as_uint(b);
    ua = (ua + 0x7fffu + ((ua >> 16) & 1u)) >> 16;
    ub = (ub + 0x7fffu + ((ub >> 16) & 1u));
    return (ua & 0xffffu) | (ub & 0xffff0000u);
}

// async global->LDS DMA, 16 B/lane: LDS dest = wave-uniform base + lane*16
static __device__ __forceinline__ void async16(const void* g, void* l) {
    __builtin_amdgcn_global_load_lds(
        (const __attribute__((address_space(1))) unsigned int*)g,
        (__attribute__((address_space(3))) unsigned int*)l, 16, 0, 0);
}

// 2^x on the transcendental pipe (scores carry log2e folded in from phase A)
static __device__ __forceinline__ float fexp2(float x) {
#if __has_builtin(__builtin_amdgcn_exp2f)
    return __builtin_amdgcn_exp2f(x);
#else
    float r; asm("v_exp_f32 %0, %1" : "=v"(r) : "v"(x)); return r;
#endif
}

#define GRID_BLOCKS 512

// ---------------------------------------------------------------------------
// Fused kernel (PLAIN launch, 512 blocks x 256 threads).
// Co-residency: LDS 50176 B -> 3 blocks/CU capacity (160 KiB/CU), VGPR 88 no
// limit => capacity 768 >= 512, all blocks resident at dispatch (in-order CP).
//
// Phase A (prepack; old 2048-block kernel repartitioned b = nb*2+j, verbatim):
//   Q: ws+0     bf16 [head][t][swz c]  rows 128B, scaled 0.125*log2(e)
//   K: ws+8MB   bf16 [head][s][swz c]  rows 128B
//   V: ws+16MB  bf16 [head][sTile(64)][c][swz s] rows 128B
//
// Manual device-scope grid barrier (NOT cooperative-groups: cg grid.sync was
// the R4 failure suspect under graph capture):
//   counter = last 4B of out, zeroed by hipMemsetAsync each launch.
//   arrive: agent-scope RELEASE fetch_add (emits vmcnt drain + L2 writeback
//           on this XCD -> all phase-A stores of this XCD visible at L3/HBM).
//   wait:   thread 0 spins on agent-scope relaxed load until >= 512.
//           Bounded spin (worst case wrong-answer, never hang).
//   exit:   __syncthreads + agent-scope ACQUIRE fence by all waves
//           (invalidates this CU's L1 + this XCD's L2 before phase-B reads).
//   The counter cell is overwritten by the owner block's epilogue float only
//   after all 512 arrivals; a late spinner reading that float sees a uint
//   >= 2^30 (any |f| >= 1e-38) -> still exits. Next launch re-zeroes.
//
// Phase B (attn; verbatim from the 132.9us passing R3 kernel).
// ---------------------------------------------------------------------------
__global__ __launch_bounds__(256, 2)
void fused(const float* __restrict__ qkv, char* __restrict__ ws,
           float* __restrict__ out)
{
    __shared__ char smem[50176];
    // Phase A: [0,33280) fp32 transpose tile 64x130
    // Phase B: [0,16384) Qs / epilogue Ob; [16384,32768) Ks[2];
    //          [32768,49152) Vs[2]; [49152,50176) Lb

    const int tid = threadIdx.x;
    const int nb  = blockIdx.x;         // 0..511

    // ======================= Phase A: prepack =======================
    {
        float* tile = (float*)smem;
#pragma unroll 1
        for (int j = 0; j < 2; ++j) {   // ---- Q/K transpose sub-blocks
            const int b = nb * 2 + j;   // 0..1023
            const int isK  = b >> 9;
            const int bb   = b & 511;
            const int headp = bb >> 4, chunk = bb & 15;
            const float* src = qkv + (size_t)headp * 192 * T_LEN
                                   + (size_t)(isK ? 64 : 0) * T_LEN;
            const int t0g = chunk * 128;
            // Q scale = ch^-0.5 (=0.125) * log2(e): phase B uses raw v_exp_f32.
            const float scale = isK ? 1.0f : 0.18033688f;
            if (j) __syncthreads();     // previous sub-tile's reads done
#pragma unroll
            for (int i = 0; i < 8; ++i) {
                int p = i * 256 + tid;
                int t4 = p & 31, c = p >> 5;
                float4 v = *(const float4*)(src + (size_t)c * T_LEN + t0g + 4 * t4);
                int a = c * 130 + 4 * t4;
                *(float2*)&tile[a]     = make_float2(v.x, v.y);
                *(float2*)&tile[a + 2] = make_float2(v.z, v.w);
            }
            __syncthreads();
            unsigned* dst = (unsigned*)ws + (size_t)isK * 2097152
                          + (size_t)headp * 65536 + (size_t)t0g * 32;
#pragma unroll
            for (int i = 0; i < 16; ++i) {
                int cp = tid & 31, t = i * 8 + (tid >> 5);
                float f0 = tile[(2 * cp) * 130 + t] * scale;
                float f1 = tile[(2 * cp + 1) * 130 + t] * scale;
                dst[t * 32 + (((cp >> 2) ^ (t & 7)) << 2) + (cp & 3)] = pack_bf16(f0, f1);
            }
        }
#pragma unroll 1
        for (int j = 0; j < 2; ++j) {   // ---- V pass-through sub-blocks
            const int b3 = nb * 2 + j;  // 0..1023
            const int headp = b3 >> 5, st = b3 & 31;
            const float* src = qkv + (size_t)headp * 192 * T_LEN + (size_t)128 * T_LEN;
            const int s0 = st * 64;
            unsigned* dst = (unsigned*)(ws + 16777216) + (size_t)b3 * 2048;
#pragma unroll
            for (int i = 0; i < 8; ++i) {
                int p = i * 256 + tid;
                int s2 = p & 31, c = p >> 5;
                float2 v = *(const float2*)(src + (size_t)c * T_LEN + s0 + 2 * s2);
                dst[c * 32 + (((s2 >> 2) ^ (c & 7)) << 2) + (s2 & 3)] = pack_bf16(v.x, v.y);
            }
        }
    }

    // ================== manual device-scope grid barrier ==================
    {
        unsigned* bar = (unsigned*)out + 4194303;   // last 4B of out (16 MB)
        __syncthreads();    // drains vmcnt: all phase-A stores complete in L2
        if (tid == 0) {
            __hip_atomic_fetch_add(bar, 1u, __ATOMIC_RELEASE,
                                   __HIP_MEMORY_SCOPE_AGENT);
            unsigned v; unsigned guard = 0;
            do {
                v = __hip_atomic_load(bar, __ATOMIC_RELAXED,
                                      __HIP_MEMORY_SCOPE_AGENT);
                __builtin_amdgcn_s_sleep(8);
            } while (v < (unsigned)GRID_BLOCKS && ++guard < (1u << 20));
        }
        __syncthreads();
        __builtin_amdgcn_fence(__ATOMIC_ACQUIRE, "agent"); // inv L1 + XCD L2
    }

    // ======================= Phase B: attn (verbatim R3) =======================
    const int wave = tid >> 6, lane = tid & 63;
    const int l31  = lane & 31, h = lane >> 5;
    const int wt   = wave & 1;          // t-half (64 t)
    const int wsx  = wave >> 1;         // s-half (32 s per iter)
    const int head = nb & 31, tb = nb >> 5;
    const int swq  = l31 & 7;

    const char* qsrc = ws + (size_t)head * 262144 + (size_t)tb * 16384;
    const char* ksrc = ws + 8388608  + (size_t)head * 262144;
    const char* vsrc = ws + 16777216 + (size_t)head * 262144;

    char*  Qs = smem;
    char*  Ks = smem + 16384;
    char*  Vs = smem + 32768;
    float* Lb = (float*)(smem + 49152);
    float* Ob = (float*)smem;           // 64c x 128t fp32, aliases Qs+Ks

    // stage Q (16 KB) + K/V tile 0
#pragma unroll
    for (int n = 0; n < 4; ++n) {
        int ch = wave * 4 + n;
        async16(qsrc + ch * 1024 + lane * 16, Qs + ch * 1024);
    }
#pragma unroll
    for (int n = 0; n < 2; ++n) {
        int ch = wave * 2 + n;
        async16(ksrc + ch * 1024 + lane * 16, Ks + ch * 1024);
        async16(vsrc + ch * 1024 + lane * 16, Vs + ch * 1024);
    }
    __syncthreads();

    // Q fragments (B operand): B[n=t=l31][k=c=8h+j], rows t = wt*64+tt*32+l31
    bf16x8 qf[2][4];
#pragma unroll
    for (int tt = 0; tt < 2; ++tt)
#pragma unroll
        for (int kb = 0; kb < 4; ++kb)
            qf[tt][kb] = *(const bf16x8*)(Qs + (wt * 64 + tt * 32 + l31) * 128
                                          + (((kb * 2 + h) ^ swq) << 4));

    f32x16 acc[2][2];                   // [ct][tt], D = O^T[c][t] partial (s-half)
#pragma unroll
    for (int ct = 0; ct < 2; ++ct)
#pragma unroll
        for (int tt = 0; tt < 2; ++tt)
#pragma unroll
            for (int r = 0; r < 16; ++r) acc[ct][tt][r] = 0.f;
    float lp0 = 0.f, lp1 = 0.f;

    for (int i = 0; i < 32; ++i) {
        const int cur = i & 1, nxt = cur ^ 1;
        if (i) __syncthreads();
        if (i < 31) {
#pragma unroll
            for (int n = 0; n < 2; ++n) {
                int ch = wave * 2 + n;
                async16(ksrc + (i + 1) * 8192 + ch * 1024 + lane * 16,
                        Ks + nxt * 8192 + ch * 1024);
                async16(vsrc + (i + 1) * 8192 + ch * 1024 + lane * 16,
                        Vs + nxt * 8192 + ch * 1024);
            }
        }

        // ---- QK^T (A=K): S^T rows s = wsx*32 + pat, cols t
        const char* KsB = Ks + cur * 8192;
        const char* VsB = Vs + cur * 8192;
        f32x16 sc0, sc1;
#pragma unroll
        for (int r = 0; r < 16; ++r) { sc0[r] = 0.f; sc1[r] = 0.f; }
        const int krow = (wsx * 32 + l31) * 128;
#pragma unroll
        for (int kb = 0; kb < 4; ++kb) {
            bf16x8 kf = *(const bf16x8*)(KsB + krow + (((kb * 2 + h) ^ swq) << 4));
            sc0 = __builtin_amdgcn_mfma_f32_32x32x16_bf16(kf, qf[0][kb], sc0, 0, 0, 0);
            sc1 = __builtin_amdgcn_mfma_f32_32x32x16_bf16(kf, qf[1][kb], sc1, 0, 0, 0);
        }

        // ---- softmax (scores pre-scaled by log2e -> raw 2^x) + bf16
        // truncation pack. l accumulated from TRUNCATED values so weights
        // sum exactly.
        unsigned p0[8], p1[8];
#pragma unroll
        for (int d = 0; d < 8; ++d) {
            unsigned a0 = __float_as_uint(fexp2(sc0[2 * d]))     & 0xffff0000u;
            unsigned a1 = __float_as_uint(fexp2(sc0[2 * d + 1])) & 0xffff0000u;
            lp0 += __uint_as_float(a0) + __uint_as_float(a1);
            p0[d] = __builtin_amdgcn_perm(a1, a0, 0x07060302u);
            unsigned b0 = __float_as_uint(fexp2(sc1[2 * d]))     & 0xffff0000u;
            unsigned b1 = __float_as_uint(fexp2(sc1[2 * d + 1])) & 0xffff0000u;
            lp1 += __uint_as_float(b0) + __uint_as_float(b1);
            p1[d] = __builtin_amdgcn_perm(b1, b0, 0x07060302u);
        }

        // ---- xor-32 exchange: C-layout -> B-layout for PV
        unsigned u00 = __shfl_xor(h ? p0[0] : p0[2], 32);
        unsigned u01 = __shfl_xor(h ? p0[1] : p0[3], 32);
        unsigned u02 = __shfl_xor(h ? p0[4] : p0[6], 32);
        unsigned u03 = __shfl_xor(h ? p0[5] : p0[7], 32);
        unsigned u10 = __shfl_xor(h ? p1[0] : p1[2], 32);
        unsigned u11 = __shfl_xor(h ? p1[1] : p1[3], 32);
        unsigned u12 = __shfl_xor(h ? p1[4] : p1[6], 32);
        unsigned u13 = __shfl_xor(h ? p1[5] : p1[7], 32);

        union PF { unsigned u[4]; bf16x8 v; };
        PF f00, f01, f10, f11;          // [tt][kb2]
        f00.u[0] = h ? u00 : p0[0]; f00.u[1] = h ? u01 : p0[1];
        f00.u[2] = h ? p0[2] : u00; f00.u[3] = h ? p0[3] : u01;
        f01.u[0] = h ? u02 : p0[4]; f01.u[1] = h ? u03 : p0[5];
        f01.u[2] = h ? p0[6] : u02; f01.u[3] = h ? p0[7] : u03;
        f10.u[0] = h ? u10 : p1[0]; f10.u[1] = h ? u11 : p1[1];
        f10.u[2] = h ? p1[2] : u10; f10.u[3] = h ? p1[3] : u11;
        f11.u[0] = h ? u12 : p1[4]; f11.u[1] = h ? u13 : p1[5];
        f11.u[2] = h ? p1[6] : u12; f11.u[3] = h ? p1[7] : u13;

        // ---- PV: O^T[c][t] += V[c][s] * P[t][s], k = s in this wave's s-half
#pragma unroll
        for (int kb2 = 0; kb2 < 2; ++kb2) {
            const bf16x8 pfv0 = kb2 ? f01.v : f00.v;
            const bf16x8 pfv1 = kb2 ? f11.v : f10.v;
#pragma unroll
            for (int ct = 0; ct < 2; ++ct) {
                bf16x8 vf = *(const bf16x8*)(VsB + (ct * 32 + l31) * 128
                              + (((wsx * 4 + kb2 * 2 + h) ^ swq) << 4));
                acc[ct][0] = __builtin_amdgcn_mfma_f32_32x32x16_bf16(vf, pfv0, acc[ct][0], 0, 0, 0);
                acc[ct][1] = __builtin_amdgcn_mfma_f32_32x32x16_bf16(vf, pfv1, acc[ct][1], 0, 0, 0);
            }
        }
    }

    __syncthreads();                    // drain last iter's LDS reads

    // ---- l: reduce over h, publish per s-half
    float lt0 = lp0 + __shfl_xor(lp0, 32);
    float lt1 = lp1 + __shfl_xor(lp1, 32);
    if (h == 0) {
        Lb[wsx * 128 + wt * 64 + l31]      = lt0;
        Lb[wsx * 128 + wt * 64 + 32 + l31] = lt1;
    }
    // ---- O: s-half-1 waves stash partials (aliases dead Qs+Ks)
    if (wsx == 1) {
#pragma unroll
        for (int ct = 0; ct < 2; ++ct)
#pragma unroll
            for (int tt = 0; tt < 2; ++tt)
#pragma unroll
                for (int r = 0; r < 16; ++r) {
                    int c = ct * 32 + (r & 3) + 8 * (r >> 2) + 4 * h;
                    Ob[c * 128 + wt * 64 + tt * 32 + l31] = acc[ct][tt][r];
                }
    }
    __syncthreads();

    if (wsx == 0) {
        const float li0 = 1.0f / (Lb[wt * 64 + l31] + Lb[128 + wt * 64 + l31]);
        const float li1 = 1.0f / (Lb[wt * 64 + 32 + l31] + Lb[128 + wt * 64 + 32 + l31]);
#pragma unroll
        for (int ct = 0; ct < 2; ++ct)
#pragma unroll
            for (int tt = 0; tt < 2; ++tt) {
                const float li = tt ? li1 : li0;
#pragma unroll
                for (int r = 0; r < 16; ++r) {
                    int c = ct * 32 + (r & 3) + 8 * (r >> 2) + 4 * h;
                    float v = acc[ct][tt][r] + Ob[c * 128 + wt * 64 + tt * 32 + l31];
                    out[((size_t)head * 64 + c) * T_LEN + tb * 128 + wt * 64 + tt * 32 + l31]
                        = v * li;
                }
            }
    }
}

extern "C" void kernel_launch(void* const* d_in, const int* in_sizes, int n_in,
                              void* d_out, int out_size, void* d_ws, size_t ws_size,
                              hipStream_t stream) {
    const float* qkv = (const float*)d_in[0];
    float* out = (float*)d_out;
    char* ws = (char*)d_ws;   // 24 MB (fully used: Q 8M | K 8M | V 8M)
    // zero the grid-barrier counter (last 4B of out; re-written by epilogue
    // after barrier use, and re-zeroed here every launch / graph replay)
    hipMemsetAsync((char*)d_out + 16777216 - 4, 0, 4, stream);
    hipLaunchKernelGGL(fused, dim3(GRID_BLOCKS), dim3(256), 0, stream,
                       qkv, ws, out);
}

// Round 6
// 128.893 us; speedup vs baseline: 1.5104x; 1.5104x over previous
//
#include <hip/hip_runtime.h>
#include <stdint.h>

#define T_LEN 2048

typedef __attribute__((ext_vector_type(8))) short bf16x8;
typedef __attribute__((ext_vector_type(16))) float f32x16;

// RNE fp32 pair -> packed bf16x2 (inputs finite normals)
static __device__ __forceinline__ unsigned pack_bf16(float a, float b) {
    unsigned ua = __float_as_uint(a);
    unsigned ub = __float_as_uint(b);
    ua = (ua + 0x7fffu + ((ua >> 16) & 1u)) >> 16;
    ub = (ub + 0x7fffu + ((ub >> 16) & 1u));
    return (ua & 0xffffu) | (ub & 0xffff0000u);
}

// async global->LDS DMA, 16 B/lane: LDS dest = wave-uniform base + lane*16
static __device__ __forceinline__ void async16(const void* g, void* l) {
    __builtin_amdgcn_global_load_lds(
        (const __attribute__((address_space(1))) unsigned int*)g,
        (__attribute__((address_space(3))) unsigned int*)l, 16, 0, 0);
}

// 2^x on the transcendental pipe (scores carry log2e folded in from prepack)
static __device__ __forceinline__ float fexp2(float x) {
#if __has_builtin(__builtin_amdgcn_exp2f)
    return __builtin_amdgcn_exp2f(x);
#else
    float r; asm("v_exp_f32 %0, %1" : "=v"(r) : "v"(x)); return r;
#endif
}

// v_permlane32_swap_b32 a, b  (in-place, inline asm — NOT the builtin, whose
// return-pair order was the R1 failure suspect):
//   a_new[0:31] = a[0:31], a_new[32:63] = b[0:31]
//   b_new[0:31] = a[32:63], b_new[32:63] = b[32:63]
// i.e. a.hi <-> b.lo. Verified word-by-word equivalent to the baseline
// shfl_xor(32) + cndmask assembly for the C->B fragment exchange.
static __device__ __forceinline__ void swap32(unsigned& a, unsigned& b) {
    asm("v_permlane32_swap_b32 %0, %1" : "+v"(a), "+v"(b));
}

// ---------------------------------------------------------------------------
// Prepack:
//   Q: ws+0     bf16 [head][t 0..2047][swz c]  rows 128B, scaled 0.125*log2(e)
//   K: ws+8MB   bf16 [head][s 0..2047][swz c]  rows 128B
//   V: ws+16MB  bf16 [head][sTile(64)][c][swz s] rows 128B
// 16B-chunk XOR swizzle within each 128B row: chunk' = chunk ^ (row&7).
// Transpose via fp32 LDS tile stride 130 (conflict-free both directions).
// ---------------------------------------------------------------------------
__global__ __launch_bounds__(256)
void prepack(const float* __restrict__ qkv, char* __restrict__ ws)
{
    __shared__ float tile[64 * 130];
    const int tid = threadIdx.x;
    const int b = blockIdx.x;

    if (b < 1024) {                       // ---- Q / K transpose
        const int isK  = b >> 9;
        const int bb   = b & 511;
        const int head = bb >> 4, chunk = bb & 15;
        const float* src = qkv + (size_t)head * 192 * T_LEN
                               + (size_t)(isK ? 64 : 0) * T_LEN;
        const int t0g = chunk * 128;
        // Q scale = ch^-0.5 (=0.125) * log2(e) so attn uses raw v_exp_f32 (2^x).
        const float scale = isK ? 1.0f : 0.18033688f;
#pragma unroll
        for (int i = 0; i < 8; ++i) {
            int p = i * 256 + tid;
            int t4 = p & 31, c = p >> 5;
            float4 v = *(const float4*)(src + (size_t)c * T_LEN + t0g + 4 * t4);
            int a = c * 130 + 4 * t4;
            *(float2*)&tile[a]     = make_float2(v.x, v.y);
            *(float2*)&tile[a + 2] = make_float2(v.z, v.w);
        }
        __syncthreads();
        unsigned* dst = (unsigned*)ws + (size_t)isK * 2097152
                      + (size_t)head * 65536 + (size_t)t0g * 32;
#pragma unroll
        for (int i = 0; i < 16; ++i) {
            int cp = tid & 31, t = i * 8 + (tid >> 5);
            float f0 = tile[(2 * cp) * 130 + t] * scale;
            float f1 = tile[(2 * cp + 1) * 130 + t] * scale;
            dst[t * 32 + (((cp >> 2) ^ (t & 7)) << 2) + (cp & 3)] = pack_bf16(f0, f1);
        }
    } else {                              // ---- V pass-through (swizzle only)
        const int b3 = b - 1024;
        const int head = b3 >> 5, st = b3 & 31;
        const float* src = qkv + (size_t)head * 192 * T_LEN + (size_t)128 * T_LEN;
        const int s0 = st * 64;
        unsigned* dst = (unsigned*)(ws + 16777216) + (size_t)b3 * 2048;
#pragma unroll
        for (int i = 0; i < 8; ++i) {
            int p = i * 256 + tid;
            int s2 = p & 31, c = p >> 5;
            float2 v = *(const float2*)(src + (size_t)c * T_LEN + s0 + 2 * s2);
            dst[c * 32 + (((s2 >> 2) ^ (c & 7)) << 2) + (s2 & 3)] = pack_bf16(v.x, v.y);
        }
    }
}

// ---------------------------------------------------------------------------
// Main: flash attention, 32x32x16 MFMA, operand-swapped QK (S^T, col=t),
// register-only P transform (permlane32_swap exchange, asm), 2x2 wave split
// (t-half x s-half), double-buffered K/V via async DMA. Block = 1 head x 128 t.
// Identical to the 132.9us passing R3 kernel except the xor-32 exchange
// (8 ds_bpermute + 40 cndmask) is replaced by 8 in-place v_permlane32_swap.
// ---------------------------------------------------------------------------
__global__ __launch_bounds__(256, 2)
void attn_fwd(const char* __restrict__ ws, float* __restrict__ out)
{
    __shared__ char smem[50176];
    // [0,16384)  Qs        (dead after qf load; epilogue O-combine buffer)
    // [16384,32768) Ks[2]  (8 KB each)
    // [32768,49152) Vs[2]
    // [49152,50176) Lb: 2 x 128 floats

    const int tid  = threadIdx.x;
    const int wave = tid >> 6, lane = tid & 63;
    const int l31  = lane & 31, h = lane >> 5;
    const int wt   = wave & 1;          // t-half (64 t)
    const int wsx  = wave >> 1;         // s-half (32 s per iter)
    const int head = blockIdx.x & 31, tb = blockIdx.x >> 5;
    const int swq  = l31 & 7;

    const char* qsrc = ws + (size_t)head * 262144 + (size_t)tb * 16384;
    const char* ksrc = ws + 8388608  + (size_t)head * 262144;
    const char* vsrc = ws + 16777216 + (size_t)head * 262144;

    char*  Qs = smem;
    char*  Ks = smem + 16384;
    char*  Vs = smem + 32768;
    float* Lb = (float*)(smem + 49152);
    float* Ob = (float*)smem;           // 64c x 128t fp32, aliases Qs+Ks

    // stage Q (16 KB) + K/V tile 0
#pragma unroll
    for (int n = 0; n < 4; ++n) {
        int ch = wave * 4 + n;
        async16(qsrc + ch * 1024 + lane * 16, Qs + ch * 1024);
    }
#pragma unroll
    for (int n = 0; n < 2; ++n) {
        int ch = wave * 2 + n;
        async16(ksrc + ch * 1024 + lane * 16, Ks + ch * 1024);
        async16(vsrc + ch * 1024 + lane * 16, Vs + ch * 1024);
    }
    __syncthreads();

    // Q fragments (B operand): B[n=t=l31][k=c=8h+j], rows t = wt*64+tt*32+l31
    bf16x8 qf[2][4];
#pragma unroll
    for (int tt = 0; tt < 2; ++tt)
#pragma unroll
        for (int kb = 0; kb < 4; ++kb)
            qf[tt][kb] = *(const bf16x8*)(Qs + (wt * 64 + tt * 32 + l31) * 128
                                          + (((kb * 2 + h) ^ swq) << 4));

    f32x16 acc[2][2];                   // [ct][tt], D = O^T[c][t] partial (s-half)
#pragma unroll
    for (int ct = 0; ct < 2; ++ct)
#pragma unroll
        for (int tt = 0; tt < 2; ++tt)
#pragma unroll
            for (int r = 0; r < 16; ++r) acc[ct][tt][r] = 0.f;
    float lp0 = 0.f, lp1 = 0.f;

    for (int i = 0; i < 32; ++i) {
        const int cur = i & 1, nxt = cur ^ 1;
        if (i) __syncthreads();
        if (i < 31) {
#pragma unroll
            for (int n = 0; n < 2; ++n) {
                int ch = wave * 2 + n;
                async16(ksrc + (i + 1) * 8192 + ch * 1024 + lane * 16,
                        Ks + nxt * 8192 + ch * 1024);
                async16(vsrc + (i + 1) * 8192 + ch * 1024 + lane * 16,
                        Vs + nxt * 8192 + ch * 1024);
            }
        }

        // ---- QK^T (A=K): S^T rows s = wsx*32 + pat, cols t
        const char* KsB = Ks + cur * 8192;
        const char* VsB = Vs + cur * 8192;
        f32x16 sc0, sc1;
#pragma unroll
        for (int r = 0; r < 16; ++r) { sc0[r] = 0.f; sc1[r] = 0.f; }
        const int krow = (wsx * 32 + l31) * 128;
#pragma unroll
        for (int kb = 0; kb < 4; ++kb) {
            bf16x8 kf = *(const bf16x8*)(KsB + krow + (((kb * 2 + h) ^ swq) << 4));
            sc0 = __builtin_amdgcn_mfma_f32_32x32x16_bf16(kf, qf[0][kb], sc0, 0, 0, 0);
            sc1 = __builtin_amdgcn_mfma_f32_32x32x16_bf16(kf, qf[1][kb], sc1, 0, 0, 0);
        }

        // ---- softmax (scores pre-scaled by log2e -> raw 2^x) + bf16
        // truncation pack (verbatim R3). l accumulated from TRUNCATED values
        // so weights sum exactly.
        union P8 { unsigned u[8]; bf16x8 v[2]; };
        P8 P0, P1;
#pragma unroll
        for (int d = 0; d < 8; ++d) {
            unsigned a0 = __float_as_uint(fexp2(sc0[2 * d]))     & 0xffff0000u;
            unsigned a1 = __float_as_uint(fexp2(sc0[2 * d + 1])) & 0xffff0000u;
            lp0 += __uint_as_float(a0) + __uint_as_float(a1);
            P0.u[d] = __builtin_amdgcn_perm(a1, a0, 0x07060302u);
            unsigned b0 = __float_as_uint(fexp2(sc1[2 * d]))     & 0xffff0000u;
            unsigned b1 = __float_as_uint(fexp2(sc1[2 * d + 1])) & 0xffff0000u;
            lp1 += __uint_as_float(b0) + __uint_as_float(b1);
            P1.u[d] = __builtin_amdgcn_perm(b1, b0, 0x07060302u);
        }

        // ---- lane-half exchange, in place: after swap32(u0,u2)/swap32(u1,u3),
        // {u[0..3]} is exactly the fragment the old shfl_xor+cndmask built.
        swap32(P0.u[0], P0.u[2]); swap32(P0.u[1], P0.u[3]);
        swap32(P0.u[4], P0.u[6]); swap32(P0.u[5], P0.u[7]);
        swap32(P1.u[0], P1.u[2]); swap32(P1.u[1], P1.u[3]);
        swap32(P1.u[4], P1.u[6]); swap32(P1.u[5], P1.u[7]);

        // ---- PV: O^T[c][t] += V[c][s] * P[t][s], k = s in this wave's s-half
#pragma unroll
        for (int kb2 = 0; kb2 < 2; ++kb2) {
            const bf16x8 pfv0 = kb2 ? P0.v[1] : P0.v[0];
            const bf16x8 pfv1 = kb2 ? P1.v[1] : P1.v[0];
#pragma unroll
            for (int ct = 0; ct < 2; ++ct) {
                bf16x8 vf = *(const bf16x8*)(VsB + (ct * 32 + l31) * 128
                              + (((wsx * 4 + kb2 * 2 + h) ^ swq) << 4));
                acc[ct][0] = __builtin_amdgcn_mfma_f32_32x32x16_bf16(vf, pfv0, acc[ct][0], 0, 0, 0);
                acc[ct][1] = __builtin_amdgcn_mfma_f32_32x32x16_bf16(vf, pfv1, acc[ct][1], 0, 0, 0);
            }
        }
    }

    __syncthreads();                    // drain last iter's LDS reads

    // ---- l: reduce over h, publish per s-half
    float lt0 = lp0 + __shfl_xor(lp0, 32);
    float lt1 = lp1 + __shfl_xor(lp1, 32);
    if (h == 0) {
        Lb[wsx * 128 + wt * 64 + l31]      = lt0;
        Lb[wsx * 128 + wt * 64 + 32 + l31] = lt1;
    }
    // ---- O: s-half-1 waves stash partials (aliases dead Qs+Ks)
    if (wsx == 1) {
#pragma unroll
        for (int ct = 0; ct < 2; ++ct)
#pragma unroll
            for (int tt = 0; tt < 2; ++tt)
#pragma unroll
                for (int r = 0; r < 16; ++r) {
                    int c = ct * 32 + (r & 3) + 8 * (r >> 2) + 4 * h;
                    Ob[c * 128 + wt * 64 + tt * 32 + l31] = acc[ct][tt][r];
                }
    }
    __syncthreads();

    if (wsx == 0) {
        const float li0 = 1.0f / (Lb[wt * 64 + l31] + Lb[128 + wt * 64 + l31]);
        const float li1 = 1.0f / (Lb[wt * 64 + 32 + l31] + Lb[128 + wt * 64 + 32 + l31]);
#pragma unroll
        for (int ct = 0; ct < 2; ++ct)
#pragma unroll
            for (int tt = 0; tt < 2; ++tt) {
                const float li = tt ? li1 : li0;
#pragma unroll
                for (int r = 0; r < 16; ++r) {
                    int c = ct * 32 + (r & 3) + 8 * (r >> 2) + 4 * h;
                    float v = acc[ct][tt][r] + Ob[c * 128 + wt * 64 + tt * 32 + l31];
                    out[((size_t)head * 64 + c) * T_LEN + tb * 128 + wt * 64 + tt * 32 + l31]
                        = v * li;
                }
            }
    }
}

extern "C" void kernel_launch(void* const* d_in, const int* in_sizes, int n_in,
                              void* d_out, int out_size, void* d_ws, size_t ws_size,
                              hipStream_t stream) {
    const float* qkv = (const float*)d_in[0];
    float* out = (float*)d_out;
    char* ws = (char*)d_ws;   // 24 MB
    hipLaunchKernelGGL(prepack, dim3(2048), dim3(256), 0, stream, qkv, ws);
    hipLaunchKernelGGL(attn_fwd, dim3(512), dim3(256), 0, stream, ws, out);
}